// Round 2
// baseline (16.604 us; speedup 1.0000x reference)
//
#include <hip/hip_runtime.h>

// RelationLoss fused single-kernel version.
// loss = mean( ((x_j-x_i)^2 - (t_j-t_i)^2)^2 ) over [C, N, N], collapsed to
// per-channel moments:
//   Sa4  = 2N*S4x - 8*S3x*S1x + 6*S2x^2
//   Sb4  = 2N*S4t - 8*S3t*S1t + 6*S2t^2
//   Sab  = 2N*Sx2t2 - 4*Sx2t*S1t - 4*Sxt2*S1x + 2*S2x*S2t + 4*Sxt^2
//   channel = Sa4 - 2*Sab + Sb4 ;  loss = sum_c(channel) / (C*N*N)
// One block per channel (64 threads = 1 wave, no LDS/barriers). Last-arriving
// block (agent-scope ticket) reduces the 128 channel terms in a FIXED tree
// order -> bitwise-deterministic output. Ticket counter zeroed per launch by a
// graph-captured 4-byte memset node.

#define C_CH 128
#define N_EL 1024

__global__ __launch_bounds__(64) void relloss_fused(
    const float* __restrict__ x, const float* __restrict__ t,
    double* __restrict__ ws, unsigned int* __restrict__ counter,
    float* __restrict__ out) {
  const int c = blockIdx.x;
  const int lane = threadIdx.x;  // 0..63, one wave per block

  const float4* __restrict__ x4 = (const float4*)(x + c * N_EL);
  const float4* __restrict__ t4 = (const float4*)(t + c * N_EL);

  double s1x = 0, s2x = 0, s3x = 0, s4x = 0;
  double s1t = 0, s2t = 0, s3t = 0, s4t = 0;
  double sxt = 0, sx2t = 0, sxt2 = 0, sx2t2 = 0;

#pragma unroll
  for (int it = 0; it < 4; ++it) {
    const float4 xv4 = x4[lane + it * 64];
    const float4 tv4 = t4[lane + it * 64];
    const float xs[4] = {xv4.x, xv4.y, xv4.z, xv4.w};
    const float ts[4] = {tv4.x, tv4.y, tv4.z, tv4.w};
#pragma unroll
    for (int j = 0; j < 4; ++j) {
      const double xv = (double)xs[j];
      const double tv = (double)ts[j];
      const double x2 = xv * xv, t2 = tv * tv;
      s1x += xv;  s2x += x2;  s3x += x2 * xv;  s4x += x2 * x2;
      s1t += tv;  s2t += t2;  s3t += t2 * tv;  s4t += t2 * t2;
      sxt += xv * tv;  sx2t += x2 * tv;  sxt2 += xv * t2;  sx2t2 += x2 * t2;
    }
  }

#define WRED(v)                                        \
  _Pragma("unroll")                                    \
  for (int o = 32; o > 0; o >>= 1) (v) += __shfl_down((v), (o), 64);

  WRED(s1x) WRED(s2x) WRED(s3x) WRED(s4x)
  WRED(s1t) WRED(s2t) WRED(s3t) WRED(s4t)
  WRED(sxt) WRED(sx2t) WRED(sxt2) WRED(sx2t2)

  unsigned int tk = 0;
  if (lane == 0) {
    const double Nn = (double)N_EL;
    const double termX = 2.0 * Nn * s4x - 8.0 * s3x * s1x + 6.0 * s2x * s2x;
    const double termT = 2.0 * Nn * s4t - 8.0 * s3t * s1t + 6.0 * s2t * s2t;
    const double cross = 2.0 * Nn * sx2t2 - 4.0 * sx2t * s1t - 4.0 * sxt2 * s1x +
                         2.0 * s2x * s2t + 4.0 * sxt * sxt;
    const double term = termX - 2.0 * cross + termT;
    __hip_atomic_store(&ws[c], term, __ATOMIC_RELEASE, __HIP_MEMORY_SCOPE_AGENT);
    tk = __hip_atomic_fetch_add(counter, 1u, __ATOMIC_ACQ_REL,
                                __HIP_MEMORY_SCOPE_AGENT);
  }
  tk = (unsigned int)__shfl((int)tk, 0, 64);

  if (tk == C_CH - 1) {
    // Last block to finish: all 128 ws[] slots are published. Reduce in a
    // fixed order (lane pairing + shuffle tree) -> deterministic bits.
    double a = __hip_atomic_load(&ws[lane], __ATOMIC_ACQUIRE,
                                 __HIP_MEMORY_SCOPE_AGENT);
    double b = __hip_atomic_load(&ws[lane + 64], __ATOMIC_ACQUIRE,
                                 __HIP_MEMORY_SCOPE_AGENT);
    double v = a + b;
    WRED(v)
    if (lane == 0) {
      // 1/(C*N*N) = 2^-27 exactly
      out[0] = (float)(v * 0x1p-27);
    }
  }
#undef WRED
}

extern "C" void kernel_launch(void* const* d_in, const int* in_sizes, int n_in,
                              void* d_out, int out_size, void* d_ws, size_t ws_size,
                              hipStream_t stream) {
  const float* x = (const float*)d_in[0];
  const float* t = (const float*)d_in[1];
  double* ws = (double*)d_ws;                                   // 128 doubles
  unsigned int* counter = (unsigned int*)((char*)d_ws + C_CH * sizeof(double));
  float* out = (float*)d_out;

  hipMemsetAsync(counter, 0, sizeof(unsigned int), stream);  // graph memset node
  relloss_fused<<<C_CH, 64, 0, stream>>>(x, t, ws, counter, out);
}

// Round 3
// 12.211 us; speedup vs baseline: 1.3598x; 1.3598x over previous
//
#include <hip/hip_runtime.h>

// RelationLoss fused single-kernel, no-reset ticket version.
// loss = mean( ((x_j-x_i)^2 - (t_j-t_i)^2)^2 ) over [C, N, N], collapsed to
// per-channel moments:
//   Sa4  = 2N*S4x - 8*S3x*S1x + 6*S2x^2
//   Sb4  = 2N*S4t - 8*S3t*S1t + 6*S2t^2
//   Sab  = 2N*Sx2t2 - 4*Sx2t*S1t - 4*Sxt2*S1x + 2*S2x*S2t + 4*Sxt^2
//   channel = Sa4 - 2*Sab + Sb4 ;  loss = sum_c(channel) / (C*N*N)
//
// One block per channel (64 threads = 1 wave; no LDS, no __syncthreads).
// Completion detection: monotonically increasing agent-scope ticket counter,
// NEVER reset. Any 128 consecutive tickets contain exactly one value
// == 127 (mod 128), and 2^32 % 128 == 0, so the block drawing that ticket is
// always the 128th (last) arrival of the current launch regardless of the
// counter's starting value (0xAA poison included). That block reduces the 128
// published channel terms in a FIXED tree order -> bitwise-deterministic out.

#define C_CH 128
#define N_EL 1024

__global__ __launch_bounds__(64) void relloss_fused(
    const float* __restrict__ x, const float* __restrict__ t,
    double* __restrict__ ws, unsigned int* __restrict__ counter,
    float* __restrict__ out) {
  const int c = blockIdx.x;
  const int lane = threadIdx.x;  // 0..63, one wave per block

  const float4* __restrict__ x4 = (const float4*)(x + c * N_EL);
  const float4* __restrict__ t4 = (const float4*)(t + c * N_EL);

  double s1x = 0, s2x = 0, s3x = 0, s4x = 0;
  double s1t = 0, s2t = 0, s3t = 0, s4t = 0;
  double sxt = 0, sx2t = 0, sxt2 = 0, sx2t2 = 0;

#pragma unroll
  for (int it = 0; it < 4; ++it) {
    const float4 xv4 = x4[lane + it * 64];
    const float4 tv4 = t4[lane + it * 64];
    const float xs[4] = {xv4.x, xv4.y, xv4.z, xv4.w};
    const float ts[4] = {tv4.x, tv4.y, tv4.z, tv4.w};
#pragma unroll
    for (int j = 0; j < 4; ++j) {
      const double xv = (double)xs[j];
      const double tv = (double)ts[j];
      const double x2 = xv * xv, t2 = tv * tv;
      s1x += xv;  s2x += x2;  s3x += x2 * xv;  s4x += x2 * x2;
      s1t += tv;  s2t += t2;  s3t += t2 * tv;  s4t += t2 * t2;
      sxt += xv * tv;  sx2t += x2 * tv;  sxt2 += xv * t2;  sx2t2 += x2 * t2;
    }
  }

#define WRED(v)                                        \
  _Pragma("unroll")                                    \
  for (int o = 32; o > 0; o >>= 1) (v) += __shfl_down((v), (o), 64);

  WRED(s1x) WRED(s2x) WRED(s3x) WRED(s4x)
  WRED(s1t) WRED(s2t) WRED(s3t) WRED(s4t)
  WRED(sxt) WRED(sx2t) WRED(sxt2) WRED(sx2t2)

  unsigned int tk = 0;
  if (lane == 0) {
    const double Nn = (double)N_EL;
    const double termX = 2.0 * Nn * s4x - 8.0 * s3x * s1x + 6.0 * s2x * s2x;
    const double termT = 2.0 * Nn * s4t - 8.0 * s3t * s1t + 6.0 * s2t * s2t;
    const double cross = 2.0 * Nn * sx2t2 - 4.0 * sx2t * s1t - 4.0 * sxt2 * s1x +
                         2.0 * s2x * s2t + 4.0 * sxt * sxt;
    const double term = termX - 2.0 * cross + termT;
    __hip_atomic_store(&ws[c], term, __ATOMIC_RELEASE, __HIP_MEMORY_SCOPE_AGENT);
    tk = __hip_atomic_fetch_add(counter, 1u, __ATOMIC_ACQ_REL,
                                __HIP_MEMORY_SCOPE_AGENT);
  }
  tk = (unsigned int)__shfl((int)tk, 0, 64);

  if ((tk & (C_CH - 1)) == C_CH - 1) {
    // 128th arrival of this launch: all 128 ws[] slots are published.
    // Fixed-order tree reduce -> deterministic bits.
    double a = __hip_atomic_load(&ws[lane], __ATOMIC_ACQUIRE,
                                 __HIP_MEMORY_SCOPE_AGENT);
    double b = __hip_atomic_load(&ws[lane + 64], __ATOMIC_ACQUIRE,
                                 __HIP_MEMORY_SCOPE_AGENT);
    double v = a + b;
    WRED(v)
    if (lane == 0) {
      // 1/(C*N*N) = 2^-27 exactly
      out[0] = (float)(v * 0x1p-27);
    }
  }
#undef WRED
}

extern "C" void kernel_launch(void* const* d_in, const int* in_sizes, int n_in,
                              void* d_out, int out_size, void* d_ws, size_t ws_size,
                              hipStream_t stream) {
  const float* x = (const float*)d_in[0];
  const float* t = (const float*)d_in[1];
  double* ws = (double*)d_ws;                                   // 128 doubles
  unsigned int* counter = (unsigned int*)((char*)d_ws + C_CH * sizeof(double));
  float* out = (float*)d_out;

  relloss_fused<<<C_CH, 64, 0, stream>>>(x, t, ws, counter, out);
}